// Round 6
// baseline (809.894 us; speedup 1.0000x reference)
//
#include <hip/hip_runtime.h>

#define NNODES 40000
#define NEDGES 640000
#define NFEAT  256
#define NHID   128

// ---- range partition geometry ----
#define RSHIFT 7                        // 128 nodes per range
#define RNODES 128
#define NR     313                      // ceil(40000/128)
#define CAPR   3000                     // slots per range; E[count]=2048, 21 sigma margin
#define PARTB  250                      // partition blocks
#define EPB    2560                     // edges per partition block (10/thread)
#define GEMM_BLOCKS (NNODES / 64)       // 625

// ---- workspace layout (bytes) ----
#define SUP_OFF  0u                     // support bf16: 40000*128*2 = 10,240,000
#define WT_OFF   10240000u              // Wt bf16: 128*256*2 = 65,536
#define RC_OFF   10305536u              // range_cursor: 313 u32 (padded)
#define EBIN_OFF 10307584u              // ebin: 313*3000*8 = 7,512,000 -> ends 17,819,584
#define WS_NEEDED 18145536u             // unchanged gate (fits)

typedef float floatx4 __attribute__((ext_vector_type(4)));
typedef __bf16 bf16x8 __attribute__((ext_vector_type(8)));
typedef unsigned short ushort8 __attribute__((ext_vector_type(8)));
union BfFrag { ushort8 s; bf16x8 b; };

__device__ __forceinline__ unsigned short f2bf(float f) {
    unsigned int u = __float_as_uint(f);
    u = (u + 0x7FFFu + ((u >> 16) & 1u)) >> 16;   // RNE
    return (unsigned short)u;
}

// ---------------------------------------------------------------------------
// K0: setup — zero range_cursor AND Wt[h][k] = bf16(W[k][h]).
// ---------------------------------------------------------------------------
__global__ __launch_bounds__(256) void setup_wt_cur(const float* __restrict__ W,
                                                    unsigned short* __restrict__ Wt,
                                                    unsigned int* __restrict__ range_cursor) {
    const int i = blockIdx.x * 256 + threadIdx.x;
    if (i < NR) range_cursor[i] = 0;
    if (i < NFEAT * NHID) {
        const int h = i >> 8;
        const int k = i & 255;
        Wt[i] = f2bf(W[k * NHID + h]);
    }
}

// ---------------------------------------------------------------------------
// K1: GEMM (blocks [0,625)) || edge partition (blocks [625,875)).
// Partition: LDS histogram over 313 dst-ranges -> ~300 global atomics/block
// (vs 640k total before) -> LDS-grouped staging -> CONTIGUOUS-run writes of
// 8B records into per-range bins. Kills the 640k random 4B stores whose
// line writebacks (~41MB) were the R0-R4 fill wall.
// ---------------------------------------------------------------------------
__global__ __launch_bounds__(256) void gemm_fill(const float* __restrict__ x,
                                                 const unsigned short* __restrict__ Wt,
                                                 unsigned short* __restrict__ support,
                                                 const int* __restrict__ ei,
                                                 const float* __restrict__ ew,
                                                 unsigned int* __restrict__ range_cursor,
                                                 unsigned long long* __restrict__ ebin) {
    const int tid = threadIdx.x;

    if (blockIdx.x >= GEMM_BLOCKS) {
        // ---- partition path ----
        __shared__ unsigned int hist[320];
        __shared__ unsigned int sA[320], sB[320];
        __shared__ unsigned int lstart[320];
        __shared__ unsigned int gbase[320];
        __shared__ unsigned int ldscur[320];
        __shared__ unsigned long long recbuf[EPB];
        __shared__ unsigned short rbuf[EPB];

        const int pb   = blockIdx.x - GEMM_BLOCKS;
        const int base = pb * EPB + tid;

        for (int i = tid; i < 320; i += 256) { hist[i] = 0; ldscur[i] = 0; }
        __syncthreads();

        // pass 1: histogram dst ranges
        int dst[10];
        #pragma unroll
        for (int j = 0; j < 10; j++) dst[j] = ei[NEDGES + base + j * 256];
        #pragma unroll
        for (int j = 0; j < 10; j++) atomicAdd(&hist[dst[j] >> RSHIFT], 1u);
        __syncthreads();

        // exclusive scan of hist (Hillis-Steele over 320, 9 passes)
        for (int i = tid; i < 320; i += 256) sA[i] = (i > 0) ? hist[i - 1] : 0u;
        __syncthreads();
        unsigned int* cur = sA;
        unsigned int* nxt = sB;
        for (int off = 1; off < 320; off <<= 1) {
            for (int i = tid; i < 320; i += 256)
                nxt[i] = cur[i] + ((i >= off) ? cur[i - off] : 0u);
            __syncthreads();
            unsigned int* t = cur; cur = nxt; nxt = t;
        }
        for (int i = tid; i < 320; i += 256) {
            lstart[i] = cur[i];
            gbase[i]  = (i < NR && hist[i] > 0u)
                        ? atomicAdd(&range_cursor[i], hist[i]) : 0u;
        }
        __syncthreads();

        // pass 2: stage records grouped by range
        int src[10];
        float w[10];
        #pragma unroll
        for (int j = 0; j < 10; j++) {
            src[j] = ei[base + j * 256];
            w[j]   = ew[base + j * 256];
        }
        #pragma unroll
        for (int j = 0; j < 10; j++) {
            const int r  = dst[j] >> RSHIFT;
            const unsigned int lr = atomicAdd(&ldscur[r], 1u);
            const unsigned int pos = lstart[r] + lr;
            recbuf[pos] = ((unsigned long long)f2bf(w[j]) << 32)
                        | ((unsigned long long)(dst[j] & (RNODES - 1)) << 16)
                        | (unsigned long long)(unsigned int)src[j];
            rbuf[pos] = (unsigned short)r;
        }
        __syncthreads();

        // writeout: consecutive staging entries of a range -> consecutive slots
        for (int i = tid; i < EPB; i += 256) {
            const int r = rbuf[i];
            const unsigned int slot = gbase[r] + ((unsigned int)i - lstart[r]);
            if (slot < CAPR)
                ebin[(size_t)r * CAPR + slot] = recbuf[i];
        }
        return;
    }

    // ---- GEMM path (unchanged) ----
    const int lane = tid & 63;
    const int wv   = tid >> 6;
    const int m    = lane & 15;
    const int quad = lane >> 4;
    const int node = blockIdx.x * 64 + wv * 16 + m;

    BfFrag afrag[8];
    const float* xrow = x + (size_t)node * NFEAT + quad * 8;
    #pragma unroll
    for (int ks = 0; ks < 8; ks++) {
        float4 f0 = *(const float4*)(xrow + ks * 32);
        float4 f1 = *(const float4*)(xrow + ks * 32 + 4);
        afrag[ks].s[0] = f2bf(f0.x); afrag[ks].s[1] = f2bf(f0.y);
        afrag[ks].s[2] = f2bf(f0.z); afrag[ks].s[3] = f2bf(f0.w);
        afrag[ks].s[4] = f2bf(f1.x); afrag[ks].s[5] = f2bf(f1.y);
        afrag[ks].s[6] = f2bf(f1.z); afrag[ks].s[7] = f2bf(f1.w);
    }

    floatx4 acc[8];
    #pragma unroll
    for (int nt = 0; nt < 8; nt++) acc[nt] = (floatx4){0.f, 0.f, 0.f, 0.f};

    #pragma unroll
    for (int nt = 0; nt < 8; nt++) {
        const unsigned short* wrow = Wt + (size_t)(nt * 16 + m) * NFEAT + quad * 8;
        #pragma unroll
        for (int ks = 0; ks < 8; ks++) {
            BfFrag bfrag;
            bfrag.s = *(const ushort8*)(wrow + ks * 32);
            acc[nt] = __builtin_amdgcn_mfma_f32_16x16x32_bf16(afrag[ks].b, bfrag.b,
                                                              acc[nt], 0, 0, 0);
        }
    }

    const int row0 = blockIdx.x * 64 + wv * 16 + quad * 4;
    #pragma unroll
    for (int nt = 0; nt < 8; nt++) {
        #pragma unroll
        for (int r = 0; r < 4; r++) {
            support[(size_t)(row0 + r) * NHID + nt * 16 + m] = f2bf(acc[nt][r]);
        }
    }
}

// ---------------------------------------------------------------------------
// K2: gather — one block per dst-range. acc[128 nodes][128 hid] f32 in LDS
// (64KB). Each wave takes a contiguous quarter of the range's records:
// broadcast 8B record read + coalesced 256B support-row read + 2 ds_add_f32
// per lane (fire-and-forget: no dep chain, HW-safe across waves).
// Epilogue: bias+relu, coalesced out writes.
// ---------------------------------------------------------------------------
__global__ __launch_bounds__(256) void gather_range(
        const unsigned int* __restrict__ range_cursor,
        const unsigned long long* __restrict__ ebin,
        const unsigned short* __restrict__ support,
        const float* __restrict__ b,
        float* __restrict__ out) {
    __shared__ float accf[RNODES * NHID];   // 64 KB

    const int r    = blockIdx.x;
    const int tid  = threadIdx.x;
    const int lane = tid & 63;
    const int wv   = tid >> 6;

    float4* acc4 = (float4*)accf;
    #pragma unroll
    for (int i = 0; i < (RNODES * NHID / 4) / 256; i++)
        acc4[tid + i * 256] = make_float4(0.f, 0.f, 0.f, 0.f);
    __syncthreads();

    unsigned int cnt = range_cursor[r];
    if (cnt > CAPR) cnt = CAPR;
    const unsigned long long* bin = ebin + (size_t)r * CAPR;

    const unsigned int kbeg = (cnt * (unsigned int)wv) >> 2;
    const unsigned int kend = (cnt * (unsigned int)(wv + 1)) >> 2;

    for (unsigned int k = kbeg; k < kend; ++k) {
        const unsigned long long rec = bin[k];            // broadcast
        const float w  = __uint_as_float(((unsigned int)(rec >> 32)) << 16);
        const int   dl = (int)((rec >> 16) & (RNODES - 1));
        const int   sc = (int)(rec & 0xFFFFu);
        const unsigned int pair =
            *(const unsigned int*)(support + (size_t)sc * NHID + lane * 2);
        const float v0 = __uint_as_float(pair << 16);
        const float v1 = __uint_as_float(pair & 0xFFFF0000u);
        atomicAdd(&accf[dl * NHID + lane * 2],     w * v0);
        atomicAdd(&accf[dl * NHID + lane * 2 + 1], w * v1);
    }
    __syncthreads();

    const int node0 = r * RNODES;
    int nn = NNODES - node0;
    if (nn > RNODES) nn = RNODES;
    const float4* b4p = (const float4*)b;
    float4*       o4  = (float4*)out;
    for (int idx = tid; idx < nn * (NHID / 4); idx += 256) {
        const int row = idx >> 5;
        const int c4  = idx & 31;
        float4 v  = acc4[row * 32 + c4];
        float4 bb = b4p[c4];
        v.x = fmaxf(v.x + bb.x, 0.f);
        v.y = fmaxf(v.y + bb.y, 0.f);
        v.z = fmaxf(v.z + bb.z, 0.f);
        v.w = fmaxf(v.w + bb.w, 0.f);
        o4[(size_t)(node0 + row) * (NHID / 4) + c4] = v;
    }
}

// ---------------------------------------------------------------------------
// Fallback path (ws too small): fp32 GEMM + atomic scatter
// ---------------------------------------------------------------------------
__global__ __launch_bounds__(256) void gemm_xw(const float* __restrict__ x,
                                               const float* __restrict__ W,
                                               float* __restrict__ support) {
    __shared__ float xs[64 * NFEAT];
    const int tid   = threadIdx.x;
    const int node0 = blockIdx.x * 64;

    const float4* xg  = (const float4*)(x + (size_t)node0 * NFEAT);
    float4*       xs4 = (float4*)xs;
    #pragma unroll
    for (int i = tid; i < 64 * (NFEAT / 4); i += 256) xs4[i] = xg[i];
    __syncthreads();

    const int hg = tid & 31;
    const int ng = tid >> 5;
    const float4* W4 = (const float4*)W;

    float4 acc[8];
    #pragma unroll
    for (int n = 0; n < 8; n++) acc[n] = make_float4(0.f, 0.f, 0.f, 0.f);

    #pragma unroll 4
    for (int k = 0; k < NFEAT; k++) {
        float4 w = W4[k * (NHID / 4) + hg];
        #pragma unroll
        for (int n = 0; n < 8; n++) {
            float xv = xs[(ng * 8 + n) * NFEAT + k];
            acc[n].x = fmaf(xv, w.x, acc[n].x);
            acc[n].y = fmaf(xv, w.y, acc[n].y);
            acc[n].z = fmaf(xv, w.z, acc[n].z);
            acc[n].w = fmaf(xv, w.w, acc[n].w);
        }
    }

    float4* out4 = (float4*)support;
    #pragma unroll
    for (int n = 0; n < 8; n++)
        out4[(size_t)(node0 + ng * 8 + n) * (NHID / 4) + hg] = acc[n];
}

__global__ __launch_bounds__(256) void scatter_edges(const int* __restrict__ ei,
                                                     const float* __restrict__ ew,
                                                     const float* __restrict__ support,
                                                     float* __restrict__ out) {
    const int tid  = threadIdx.x;
    const int lane = tid & 31;
    const int e    = blockIdx.x * 8 + (tid >> 5);
    const int   src = ei[e];
    const int   dst = ei[NEDGES + e];
    const float w   = ew[e];
    const float4* s4 = (const float4*)support;
    float4 v = s4[(size_t)src * (NHID / 4) + lane];
    float* o = out + (size_t)dst * NHID + lane * 4;
    atomicAdd(o + 0, v.x * w);
    atomicAdd(o + 1, v.y * w);
    atomicAdd(o + 2, v.z * w);
    atomicAdd(o + 3, v.w * w);
}

__global__ __launch_bounds__(256) void finalize(float* __restrict__ out,
                                                const float* __restrict__ b) {
    const int i = blockIdx.x * 256 + threadIdx.x;
    float4*       o4 = (float4*)out;
    const float4* b4 = (const float4*)b;
    float4 v  = o4[i];
    float4 bb = b4[i & 31];
    v.x = fmaxf(v.x + bb.x, 0.f);
    v.y = fmaxf(v.y + bb.y, 0.f);
    v.z = fmaxf(v.z + bb.z, 0.f);
    v.w = fmaxf(v.w + bb.w, 0.f);
    o4[i] = v;
}

extern "C" void kernel_launch(void* const* d_in, const int* in_sizes, int n_in,
                              void* d_out, int out_size, void* d_ws, size_t ws_size,
                              hipStream_t stream) {
    const float* x  = (const float*)d_in[0];
    const int*   ei = (const int*)d_in[1];
    const float* ew = (const float*)d_in[2];
    const float* W  = (const float*)d_in[3];
    const float* b  = (const float*)d_in[4];
    float*       out = (float*)d_out;

    char* ws = (char*)d_ws;

    if (ws_size >= WS_NEEDED) {
        unsigned short*     support = (unsigned short*)(ws + SUP_OFF);
        unsigned short*     Wt      = (unsigned short*)(ws + WT_OFF);
        unsigned int*       rcur    = (unsigned int*)(ws + RC_OFF);
        unsigned long long* ebin    = (unsigned long long*)(ws + EBIN_OFF);

        setup_wt_cur<<<160, 256, 0, stream>>>(W, Wt, rcur);
        gemm_fill<<<GEMM_BLOCKS + PARTB, 256, 0, stream>>>(
            x, Wt, support, ei, ew, rcur, ebin);
        gather_range<<<NR, 256, 0, stream>>>(rcur, ebin, support, b, out);
    } else {
        float* support = (float*)(ws + SUP_OFF);
        gemm_xw<<<NNODES / 64, 256, 0, stream>>>(x, W, support);
        hipMemsetAsync(d_out, 0, (size_t)out_size * sizeof(float), stream);
        scatter_edges<<<NEDGES / 8, 256, 0, stream>>>(ei, ew, support, out);
        finalize<<<out_size / 4 / 256, 256, 0, stream>>>(out, b);
    }
}